// Round 3
// baseline (957.189 us; speedup 1.0000x reference)
//
#include <hip/hip_runtime.h>

using half8  = __attribute__((ext_vector_type(8))) _Float16;
using half4v = __attribute__((ext_vector_type(4))) _Float16;
using f32x4  = __attribute__((ext_vector_type(4))) float;

#define MFMA16(a,b,c) __builtin_amdgcn_mfma_f32_16x16x32_f16((a),(b),(c),0,0,0)

__device__ __forceinline__ float fexp_(float x){ return exp2f(x * 1.4426950408889634f); }
__device__ __forceinline__ float sig_(float x){ return __builtin_amdgcn_rcpf(1.0f + fexp_(-x)); }
__device__ __forceinline__ float tanh_(float x){
  float t = fexp_(-2.0f * fabsf(x));
  float r = (1.0f - t) * __builtin_amdgcn_rcpf(1.0f + t);
  return copysignf(r, x);
}

// ---------------- K0: weight transposes / fp16 packing ----------------
__global__ void k0_prep(const float* __restrict__ Wk, const float* __restrict__ Wr,
                        const float* __restrict__ Wd, _Float16* __restrict__ wkt,
                        _Float16* __restrict__ wrtb, _Float16* __restrict__ wdt)
{
  int i = blockIdx.x * 256 + threadIdx.x;
  if (i < 1024*320) {
    int g = i / 320, k = i - g*320;
    wkt[i] = (_Float16)((k < 300) ? Wk[k*1024 + g] : 0.0f);
  }
  if (i < 4*256*256) {
    int jt = i >> 16, r = (i >> 8) & 255, k = i & 255;
    int g = ((r >> 6) << 8) + (jt << 6) + (r & 63);
    wrtb[i] = (_Float16)Wr[k*1024 + g];
  }
  if (i < 256*512) {
    int d = i >> 9, k = i & 511;
    wdt[i] = (_Float16)Wd[k*256 + d];
  }
}

// ---------------- K1: embW = emb @ Wk + b  -> embw[v][1024], col = 256*jt + 64*gate + i
__global__ __launch_bounds__(512, 2) void k1_embw(
    const float* __restrict__ emb, const float* __restrict__ bias,
    const _Float16* __restrict__ wkt, _Float16* __restrict__ embw)
{
  __shared__ _Float16 a_s[1024][40];
  __shared__ _Float16 e_s[64][40];
  const int tid = threadIdx.x;
  const int wv = tid >> 6, ln = tid & 63, l16 = ln & 15, lq = ln >> 4;
  const int v0 = blockIdx.x * 64;

  f32x4 acc[8][4];
  #pragma unroll
  for (int ml=0;ml<8;++ml)
    #pragma unroll
    for (int nt=0;nt<4;++nt){ f32x4 z0; z0[0]=0.f;z0[1]=0.f;z0[2]=0.f;z0[3]=0.f; acc[ml][nt]=z0; }

  const int evv = tid >> 2;
  const int ekq = tid & 3;

  for (int c = 0; c < 10; ++c) {
    {
      const uint4* sp  = (const uint4*)(wkt + (size_t)(2*tid)*320 + 32*c);
      uint4 r0=sp[0], r1=sp[1], r2=sp[2], r3=sp[3];
      const uint4* sp2 = (const uint4*)(wkt + (size_t)(2*tid+1)*320 + 32*c);
      uint4 r4=sp2[0], r5=sp2[1], r6=sp2[2], r7=sp2[3];
      uint4* dq  = (uint4*)&a_s[2*tid][0];
      dq[0]=r0; dq[1]=r1; dq[2]=r2; dq[3]=r3;
      uint4* dq2 = (uint4*)&a_s[2*tid+1][0];
      dq2[0]=r4; dq2[1]=r5; dq2[2]=r6; dq2[3]=r7;
    }
    if (tid < 256) {
      int vsrc = v0 + evv; if (vsrc > 19999) vsrc = 19999;
      float f0,f1,f2,f3,f4,f5,f6,f7;
      if (c < 9) {
        const float4* sp = (const float4*)(emb + (size_t)vsrc*300 + 32*c + 8*ekq);
        float4 fa = sp[0], fb = sp[1];
        f0=fa.x; f1=fa.y; f2=fa.z; f3=fa.w; f4=fb.x; f5=fb.y; f6=fb.z; f7=fb.w;
      } else {
        const float* sp = emb + (size_t)vsrc*300;
        int k0 = 288 + 8*ekq;
        f0 = (k0+0<300)? sp[k0+0] : 0.f;  f1 = (k0+1<300)? sp[k0+1] : 0.f;
        f2 = (k0+2<300)? sp[k0+2] : 0.f;  f3 = (k0+3<300)? sp[k0+3] : 0.f;
        f4 = (k0+4<300)? sp[k0+4] : 0.f;  f5 = (k0+5<300)? sp[k0+5] : 0.f;
        f6 = (k0+6<300)? sp[k0+6] : 0.f;  f7 = (k0+7<300)? sp[k0+7] : 0.f;
      }
      half8 hv;
      hv[0]=(_Float16)f0; hv[1]=(_Float16)f1; hv[2]=(_Float16)f2; hv[3]=(_Float16)f3;
      hv[4]=(_Float16)f4; hv[5]=(_Float16)f5; hv[6]=(_Float16)f6; hv[7]=(_Float16)f7;
      *(half8*)&e_s[evv][8*ekq] = hv;
    }
    __syncthreads();
    half8 bf[4];
    #pragma unroll
    for (int nt=0;nt<4;++nt) bf[nt] = *(const half8*)&e_s[16*nt + l16][8*lq];
    #pragma unroll
    for (int ml=0;ml<8;++ml) {
      half8 af = *(const half8*)&a_s[16*(8*wv+ml) + l16][8*lq];
      #pragma unroll
      for (int nt=0;nt<4;++nt) acc[ml][nt] = MFMA16(af, bf[nt], acc[ml][nt]);
    }
    __syncthreads();
  }
  #pragma unroll
  for (int ml=0;ml<8;++ml) {
    int g0 = 16*(8*wv+ml) + 4*lq;
    float4 bv = *(const float4*)&bias[g0];
    float bvr[4] = {bv.x,bv.y,bv.z,bv.w};
    int jt = (g0 >> 6) & 3;
    int c0 = ((g0 >> 8) << 6) + (g0 & 63);
    #pragma unroll
    for (int nt=0;nt<4;++nt) {
      int v = v0 + 16*nt + l16;
      if (v < 20000) {
        half4v hv;
        hv[0]=(_Float16)(acc[ml][nt][0]+bvr[0]);
        hv[1]=(_Float16)(acc[ml][nt][1]+bvr[1]);
        hv[2]=(_Float16)(acc[ml][nt][2]+bvr[2]);
        hv[3]=(_Float16)(acc[ml][nt][3]+bvr[3]);
        *(half4v*)&embw[(size_t)v*1024 + 256*jt + c0] = hv;
      }
    }
  }
}

// ---------------- K2: fused bi-LSTM + dense + attention, 1 block = 1 card ----------------
// 80 seq rows: 0..39 fw paths, 40..79 bw paths. zT = WrT(A, direct from L2) x hT(B, LDS).
// Occupancy is LDS-bound at 1 block/CU = 2 waves/EU; amdgpu_waves_per_eu(2,2) tells the
// register allocator so (R2's __launch_bounds__ made it allocate 128 VGPRs and spill
// ~140MB of scratch per dispatch — WRITE_SIZE 141MB, the round's entire cost).

#define NEXT_IDX(T) do { \
    _Pragma("unroll") for (int nt=0;nt<3;++nt) if (nt<NT) \
      idxc[nt] = x[xb + pA[nt]*12 + (dirA[nt] ? 11-(T) : (T))]; \
  } while(0)

#define ISSUE_E(JT) do { \
    _Pragma("unroll") for (int nt=0;nt<3;++nt) if (nt<NT) { \
      const _Float16* ep = embw + (size_t)idxc[nt]*1024 + 256*(JT) + ebase; \
      _Pragma("unroll") for (int g=0;g<4;++g) eR[g][nt] = *(const half4v*)(ep + 64*g); \
    } } while(0)

#define ACC_FROM_E() do { \
    _Pragma("unroll") for (int g=0;g<4;++g) \
      _Pragma("unroll") for (int nt=0;nt<3;++nt) if (nt<NT) { \
        f32x4 a0; a0[0]=(float)eR[g][nt][0]; a0[1]=(float)eR[g][nt][1]; \
        a0[2]=(float)eR[g][nt][2]; a0[3]=(float)eR[g][nt][3]; acc[g][nt]=a0; \
      } } while(0)

#define ISSUE_A(P,JT,KQ) do { \
    const _Float16* ap = wrtb + abase + 65536*(JT) + 64*(KQ); \
    _Pragma("unroll") for (int g=0;g<4;++g) { \
      aR[P][2*g+0] = *(const half8*)(ap + 16384*g); \
      aR[P][2*g+1] = *(const half8*)(ap + 16384*g + 32); \
    } } while(0)

#define MFMAQ(P,KQ) do { \
    _Pragma("unroll") for (int kk2=0;kk2<2;++kk2) { \
      half8 bF[3]; \
      _Pragma("unroll") for (int nt=0;nt<3;++nt) if (nt<NT) \
        bF[nt] = *(const half8*)(hc + bbase[nt] + ((64*(KQ)+32*kk2+8*lq) ^ bswz[nt])); \
      _Pragma("unroll") for (int g=0;g<4;++g) \
        _Pragma("unroll") for (int nt=0;nt<3;++nt) if (nt<NT) \
          acc[g][nt] = MFMA16(aR[P][2*g+kk2], bF[nt], acc[g][nt]); \
    } } while(0)

#define GATES(JT) do { \
    _Pragma("unroll") for (int nt=0;nt<3;++nt) if (nt<NT) { \
      half4v hv; \
      _Pragma("unroll") for (int r=0;r<4;++r) { \
        float zi=acc[0][nt][r], zf=acc[1][nt][r], zg=acc[2][nt][r], zo=acc[3][nt][r]; \
        float cn = sig_(zf)*c_reg[JT][nt][r] + sig_(zi)*tanh_(zg); \
        c_reg[JT][nt][r]=cn; hv[r]=(_Float16)(sig_(zo)*tanh_(cn)); \
      } \
      *(half4v*)(hn + bbase[nt] + ((64*(JT)+16*hq+4*lq) ^ bswz[nt])) = hv; \
    } } while(0)

__global__ void
__attribute__((amdgpu_flat_work_group_size(512, 512)))
__attribute__((amdgpu_waves_per_eu(2, 2)))
k2_main(
    const int* __restrict__ x, const float* __restrict__ bd,
    const float* __restrict__ att, const _Float16* __restrict__ embw,
    const _Float16* __restrict__ wrtb, const _Float16* __restrict__ wdt,
    float* __restrict__ out)
{
  __shared__ _Float16 h_s[2][80][256];
  __shared__ float att_s[256];
  __shared__ float sc_s[40];
  __shared__ float wgt[40];

  const int b   = blockIdx.x;
  const int tid = threadIdx.x;
  const int wv  = tid >> 6;
  const int ln  = tid & 63;
  const int l16 = ln & 15;
  const int lq  = ln >> 4;
  const int hq  = wv & 3;
  const int np2 = wv >> 2;
  const int NT  = np2 ? 2 : 3;

  if (tid < 256) att_s[tid] = att[tid];

  int pA[3] = {0,0,0}, dirA[3] = {0,0,0};
  int bbase[3] = {0,0,0}, bswz[3] = {0,0,0};
  #pragma unroll
  for (int nt=0;nt<3;++nt) if (nt<NT) {
    int s = 48*np2 + 16*nt + l16;
    dirA[nt] = (s >= 40); pA[nt] = s - 40*(s>=40);
    bbase[nt] = s*256; bswz[nt] = (s&7)<<3;
  }
  const int xb = b*480;
  const int ebase = 16*hq + 4*lq;
  const size_t abase = (size_t)(16*hq + l16)*256 + 8*lq;

  float c_reg[4][3][4];
  #pragma unroll
  for (int a1=0;a1<4;++a1)
    #pragma unroll
    for (int a2=0;a2<3;++a2)
      #pragma unroll
      for (int a3=0;a3<4;++a3) c_reg[a1][a2][a3] = 0.0f;

  half4v eR[4][3];
  half8  aR[2][8];
  f32x4  acc[4][3];
  int idxc[3] = {0,0,0};

  NEXT_IDX(0);
  ISSUE_E(0);

  for (int t = 0; t < 12; ++t) {
    const _Float16* hc = &h_s[t&1][0][0];
    _Float16*       hn = &h_s[(t+1)&1][0][0];
    const bool first = (t == 0), last = (t == 11);
    #pragma unroll
    for (int jt = 0; jt < 4; ++jt) {
      ACC_FROM_E();
      if (jt < 3) { ISSUE_E(jt+1); }
      else if (!last) { NEXT_IDX(t+1); ISSUE_E(0); }
      if (!first) {
        #pragma unroll
        for (int kq = 0; kq < 4; ++kq) {
          if (kq < 3)      { ISSUE_A((kq&1)^1, jt, kq+1); }
          else if (jt < 3) { ISSUE_A((kq&1)^1, jt+1, 0); }
          else if (!last)  { ISSUE_A((kq&1)^1, 0, 0); }
          MFMAQ(kq&1, kq);
        }
      } else if (jt == 3) {
        ISSUE_A(0, 0, 0);   // prime A pipeline for t=1
      }
      GATES(jt);
    }
    __syncthreads();
  }

  // ---------- dense: denseT[256 d][48 p] = tanh(WdT x stateT + bd), barrier-free ----------
  const _Float16* hs0 = &h_s[0][0][0];   // final state lives in buf 0
  f32x4 dacc[2][3];
  #pragma unroll
  for (int ml=0;ml<2;++ml)
    #pragma unroll
    for (int nt=0;nt<3;++nt){ f32x4 z0; z0[0]=0.f;z0[1]=0.f;z0[2]=0.f;z0[3]=0.f; dacc[ml][nt]=z0; }
  int pD2[3];
  #pragma unroll
  for (int nt=0;nt<3;++nt){ int p = 16*nt + l16; pD2[nt] = (p < 40) ? p : 39; }

  #pragma unroll
  for (int kq = 0; kq < 8; ++kq) {
    const _Float16* wp0 = wdt + (size_t)(16*(2*wv+0)+l16)*512 + 64*kq + 8*lq;
    const _Float16* wp1 = wdt + (size_t)(16*(2*wv+1)+l16)*512 + 64*kq + 8*lq;
    half8 ad0a = *(const half8*)(wp0), ad0b = *(const half8*)(wp0 + 32);
    half8 ad1a = *(const half8*)(wp1), ad1b = *(const half8*)(wp1 + 32);
    #pragma unroll
    for (int kk2=0;kk2<2;++kk2) {
      half8 bD[3];
      #pragma unroll
      for (int nt=0;nt<3;++nt) {
        int rowD = pD2[nt] + 40*(kq>>2);
        bD[nt] = *(const half8*)(hs0 + rowD*256 + ((64*(kq&3)+32*kk2+8*lq) ^ ((rowD&7)<<3)));
      }
      half8 a0 = kk2 ? ad0b : ad0a;
      half8 a1 = kk2 ? ad1b : ad1a;
      #pragma unroll
      for (int nt=0;nt<3;++nt) {
        dacc[0][nt] = MFMA16(a0, bD[nt], dacc[0][nt]);
        dacc[1][nt] = MFMA16(a1, bD[nt], dacc[1][nt]);
      }
    }
  }
  _Float16* d_s = (_Float16*)&h_s[1][0][0];   // overlay dead buffer: [256 d][56]
  #pragma unroll
  for (int ml = 0; ml < 2; ++ml) {
    int d0 = 16*(2*wv+ml) + 4*lq;
    float4 bv = *(const float4*)&bd[d0];
    float bvr[4] = {bv.x, bv.y, bv.z, bv.w};
    #pragma unroll
    for (int nt = 0; nt < 3; ++nt) {
      int p = 16*nt + l16;
      #pragma unroll
      for (int r = 0; r < 4; ++r) {
        float val = tanh_(dacc[ml][nt][r] + bvr[r]);
        d_s[(d0 + r)*56 + p] = (_Float16)val;
      }
    }
  }
  __syncthreads();
  // ---------- attention: scores by all 8 waves (5 paths each), softmax, weighted sum ----------
  {
    #pragma unroll
    for (int q = 0; q < 5; ++q) {
      int pp = 5*wv + q;
      float s = 0.0f;
      #pragma unroll
      for (int j = 0; j < 4; ++j) {
        int d = 64*j + ln;
        s += (float)d_s[d*56 + pp] * att_s[d];
      }
      #pragma unroll
      for (int off = 32; off > 0; off >>= 1) s += __shfl_xor(s, off);
      if (ln == 0) sc_s[pp] = s;
    }
  }
  __syncthreads();
  if (wv == 0) {
    float sc = (ln < 40) ? sc_s[ln] : -1e30f;
    float m = sc;
    #pragma unroll
    for (int off = 32; off > 0; off >>= 1) m = fmaxf(m, __shfl_xor(m, off));
    float e = __expf(sc - m);
    float se = e;
    #pragma unroll
    for (int off = 32; off > 0; off >>= 1) se += __shfl_xor(se, off);
    if (ln < 40) wgt[ln] = e / se;
  }
  __syncthreads();
  if (tid < 256) {
    float o = 0.0f;
    #pragma unroll 8
    for (int p = 0; p < 40; ++p) o += wgt[p] * (float)d_s[tid*56 + p];
    out[b*256 + tid] = o;
  }
}

extern "C" void kernel_launch(void* const* d_in, const int* in_sizes, int n_in,
                              void* d_out, int out_size, void* d_ws, size_t ws_size,
                              hipStream_t stream)
{
  (void)in_sizes; (void)n_in; (void)out_size;
  const int*   x   = (const int*)  d_in[0];
  const float* emb = (const float*)d_in[1];
  const float* Wk  = (const float*)d_in[2];
  const float* Wr  = (const float*)d_in[3];
  const float* bi  = (const float*)d_in[4];
  const float* Wd  = (const float*)d_in[5];
  const float* bd  = (const float*)d_in[6];
  const float* att = (const float*)d_in[7];
  float* out = (float*)d_out;

  if (ws_size < 42401792u) return;   // need 42.4 MB scratch
  char* ws = (char*)d_ws;
  _Float16* embw = (_Float16*)(ws + 0);          // [20000][1024] fp16 = 40,960,000 B
  _Float16* wrtb = (_Float16*)(ws + 40960000);   // [4][256][256] fp16 =    524,288 B
  _Float16* wkt  = (_Float16*)(ws + 41484288);   // [1024][320]   fp16 =    655,360 B
  _Float16* wdt  = (_Float16*)(ws + 42139648);   // [256][512]    fp16 =    262,144 B

  k0_prep<<<dim3(1280), dim3(256), 0, stream>>>(Wk, Wr, Wd, wkt, wrtb, wdt);
  k1_embw<<<dim3(313), dim3(512), 0, stream>>>(emb, bi, wkt, embw);
  k2_main<<<dim3(256), dim3(512), 0, stream>>>(x, bd, att, embw, wrtb, wdt, out);
}

// Round 4
// 956.881 us; speedup vs baseline: 1.0003x; 1.0003x over previous
//
#include <hip/hip_runtime.h>

using half8  = __attribute__((ext_vector_type(8))) _Float16;
using half4v = __attribute__((ext_vector_type(4))) _Float16;
using f32x4  = __attribute__((ext_vector_type(4))) float;

#define MFMA16(a,b,c) __builtin_amdgcn_mfma_f32_16x16x32_f16((a),(b),(c),0,0,0)

__device__ __forceinline__ float fexp_(float x){ return exp2f(x * 1.4426950408889634f); }
__device__ __forceinline__ float sig_(float x){ return __builtin_amdgcn_rcpf(1.0f + fexp_(-x)); }
__device__ __forceinline__ float tanh_(float x){
  float t = fexp_(-2.0f * fabsf(x));
  float r = (1.0f - t) * __builtin_amdgcn_rcpf(1.0f + t);
  return copysignf(r, x);
}

// ---------------- K0: weight transposes / fp16 packing ----------------
__global__ void k0_prep(const float* __restrict__ Wk, const float* __restrict__ Wr,
                        const float* __restrict__ Wd, _Float16* __restrict__ wkt,
                        _Float16* __restrict__ wrtb, _Float16* __restrict__ wdt)
{
  int i = blockIdx.x * 256 + threadIdx.x;
  if (i < 1024*320) {
    int g = i / 320, k = i - g*320;
    wkt[i] = (_Float16)((k < 300) ? Wk[k*1024 + g] : 0.0f);
  }
  if (i < 4*256*256) {
    int jt = i >> 16, r = (i >> 8) & 255, k = i & 255;
    int g = ((r >> 6) << 8) + (jt << 6) + (r & 63);
    wrtb[i] = (_Float16)Wr[k*1024 + g];
  }
  if (i < 256*512) {
    int d = i >> 9, k = i & 511;
    wdt[i] = (_Float16)Wd[k*256 + d];
  }
}

// ---------------- K1: embW = emb @ Wk + b  -> embw[v][1024], col = 256*jt + 64*gate + i
__global__ __launch_bounds__(512, 2) void k1_embw(
    const float* __restrict__ emb, const float* __restrict__ bias,
    const _Float16* __restrict__ wkt, _Float16* __restrict__ embw)
{
  __shared__ _Float16 a_s[1024][40];
  __shared__ _Float16 e_s[64][40];
  const int tid = threadIdx.x;
  const int wv = tid >> 6, ln = tid & 63, l16 = ln & 15, lq = ln >> 4;
  const int v0 = blockIdx.x * 64;

  f32x4 acc[8][4];
  #pragma unroll
  for (int ml=0;ml<8;++ml)
    #pragma unroll
    for (int nt=0;nt<4;++nt){ f32x4 z0; z0[0]=0.f;z0[1]=0.f;z0[2]=0.f;z0[3]=0.f; acc[ml][nt]=z0; }

  const int evv = tid >> 2;
  const int ekq = tid & 3;

  for (int c = 0; c < 10; ++c) {
    {
      const uint4* sp  = (const uint4*)(wkt + (size_t)(2*tid)*320 + 32*c);
      uint4 r0=sp[0], r1=sp[1], r2=sp[2], r3=sp[3];
      const uint4* sp2 = (const uint4*)(wkt + (size_t)(2*tid+1)*320 + 32*c);
      uint4 r4=sp2[0], r5=sp2[1], r6=sp2[2], r7=sp2[3];
      uint4* dq  = (uint4*)&a_s[2*tid][0];
      dq[0]=r0; dq[1]=r1; dq[2]=r2; dq[3]=r3;
      uint4* dq2 = (uint4*)&a_s[2*tid+1][0];
      dq2[0]=r4; dq2[1]=r5; dq2[2]=r6; dq2[3]=r7;
    }
    if (tid < 256) {
      int vsrc = v0 + evv; if (vsrc > 19999) vsrc = 19999;
      float f0,f1,f2,f3,f4,f5,f6,f7;
      if (c < 9) {
        const float4* sp = (const float4*)(emb + (size_t)vsrc*300 + 32*c + 8*ekq);
        float4 fa = sp[0], fb = sp[1];
        f0=fa.x; f1=fa.y; f2=fa.z; f3=fa.w; f4=fb.x; f5=fb.y; f6=fb.z; f7=fb.w;
      } else {
        const float* sp = emb + (size_t)vsrc*300;
        int k0 = 288 + 8*ekq;
        f0 = (k0+0<300)? sp[k0+0] : 0.f;  f1 = (k0+1<300)? sp[k0+1] : 0.f;
        f2 = (k0+2<300)? sp[k0+2] : 0.f;  f3 = (k0+3<300)? sp[k0+3] : 0.f;
        f4 = (k0+4<300)? sp[k0+4] : 0.f;  f5 = (k0+5<300)? sp[k0+5] : 0.f;
        f6 = (k0+6<300)? sp[k0+6] : 0.f;  f7 = (k0+7<300)? sp[k0+7] : 0.f;
      }
      half8 hv;
      hv[0]=(_Float16)f0; hv[1]=(_Float16)f1; hv[2]=(_Float16)f2; hv[3]=(_Float16)f3;
      hv[4]=(_Float16)f4; hv[5]=(_Float16)f5; hv[6]=(_Float16)f6; hv[7]=(_Float16)f7;
      *(half8*)&e_s[evv][8*ekq] = hv;
    }
    __syncthreads();
    half8 bf[4];
    #pragma unroll
    for (int nt=0;nt<4;++nt) bf[nt] = *(const half8*)&e_s[16*nt + l16][8*lq];
    #pragma unroll
    for (int ml=0;ml<8;++ml) {
      half8 af = *(const half8*)&a_s[16*(8*wv+ml) + l16][8*lq];
      #pragma unroll
      for (int nt=0;nt<4;++nt) acc[ml][nt] = MFMA16(af, bf[nt], acc[ml][nt]);
    }
    __syncthreads();
  }
  #pragma unroll
  for (int ml=0;ml<8;++ml) {
    int g0 = 16*(8*wv+ml) + 4*lq;
    float4 bv = *(const float4*)&bias[g0];
    float bvr[4] = {bv.x,bv.y,bv.z,bv.w};
    int jt = (g0 >> 6) & 3;
    int c0 = ((g0 >> 8) << 6) + (g0 & 63);
    #pragma unroll
    for (int nt=0;nt<4;++nt) {
      int v = v0 + 16*nt + l16;
      if (v < 20000) {
        half4v hv;
        hv[0]=(_Float16)(acc[ml][nt][0]+bvr[0]);
        hv[1]=(_Float16)(acc[ml][nt][1]+bvr[1]);
        hv[2]=(_Float16)(acc[ml][nt][2]+bvr[2]);
        hv[3]=(_Float16)(acc[ml][nt][3]+bvr[3]);
        *(half4v*)&embw[(size_t)v*1024 + 256*jt + c0] = hv;
      }
    }
  }
}

// ---------------- K2: fused bi-LSTM + dense + attention, 1 block = 1 card ----------------
// 80 seq rows: 0..39 fw paths, 40..79 bw paths. zT = WrT(A, direct from L2) x hT(B, LDS).
// Register budget: occupancy is LDS-bound (83KB -> 1 block/CU = 2 waves/EU), so give the
// allocator min-waves=1 (budget up to 512 total). With (512,2) the gfx950 backend split
// the file 128 Arch + 128 Acc and spilled ~40 arch regs -> 148MB/dispatch scratch writes
// (R2/R3 WRITE_SIZE). Looser bound lets the arch half grow; occupancy unchanged.

#define NEXT_IDX(T) do { \
    _Pragma("unroll") for (int nt=0;nt<3;++nt) if (nt<NT) \
      idxc[nt] = x[xb + pA[nt]*12 + (dirA[nt] ? 11-(T) : (T))]; \
  } while(0)

#define ISSUE_E(JT) do { \
    _Pragma("unroll") for (int nt=0;nt<3;++nt) if (nt<NT) { \
      const _Float16* ep = embw + (size_t)idxc[nt]*1024 + 256*(JT) + ebase; \
      _Pragma("unroll") for (int g=0;g<4;++g) eR[g][nt] = *(const half4v*)(ep + 64*g); \
    } } while(0)

#define ACC_FROM_E() do { \
    _Pragma("unroll") for (int g=0;g<4;++g) \
      _Pragma("unroll") for (int nt=0;nt<3;++nt) if (nt<NT) { \
        f32x4 a0; a0[0]=(float)eR[g][nt][0]; a0[1]=(float)eR[g][nt][1]; \
        a0[2]=(float)eR[g][nt][2]; a0[3]=(float)eR[g][nt][3]; acc[g][nt]=a0; \
      } } while(0)

#define ISSUE_A(P,JT,KQ) do { \
    const _Float16* ap = wrtb + abase + 65536*(JT) + 64*(KQ); \
    _Pragma("unroll") for (int g=0;g<4;++g) { \
      aR[P][2*g+0] = *(const half8*)(ap + 16384*g); \
      aR[P][2*g+1] = *(const half8*)(ap + 16384*g + 32); \
    } } while(0)

#define MFMAQ(P,KQ) do { \
    _Pragma("unroll") for (int kk2=0;kk2<2;++kk2) { \
      half8 bF[3]; \
      _Pragma("unroll") for (int nt=0;nt<3;++nt) if (nt<NT) \
        bF[nt] = *(const half8*)(hc + bbase[nt] + ((64*(KQ)+32*kk2+8*lq) ^ bswz[nt])); \
      _Pragma("unroll") for (int g=0;g<4;++g) \
        _Pragma("unroll") for (int nt=0;nt<3;++nt) if (nt<NT) \
          acc[g][nt] = MFMA16(aR[P][2*g+kk2], bF[nt], acc[g][nt]); \
    } } while(0)

#define GATES(JT) do { \
    _Pragma("unroll") for (int nt=0;nt<3;++nt) if (nt<NT) { \
      half4v hv; \
      _Pragma("unroll") for (int r=0;r<4;++r) { \
        float zi=acc[0][nt][r], zf=acc[1][nt][r], zg=acc[2][nt][r], zo=acc[3][nt][r]; \
        float cn = sig_(zf)*c_reg[JT][nt][r] + sig_(zi)*tanh_(zg); \
        c_reg[JT][nt][r]=cn; hv[r]=(_Float16)(sig_(zo)*tanh_(cn)); \
      } \
      *(half4v*)(hn + bbase[nt] + ((64*(JT)+16*hq+4*lq) ^ bswz[nt])) = hv; \
    } } while(0)

__global__ __launch_bounds__(512, 1) void k2_main(
    const int* __restrict__ x, const float* __restrict__ bd,
    const float* __restrict__ att, const _Float16* __restrict__ embw,
    const _Float16* __restrict__ wrtb, const _Float16* __restrict__ wdt,
    float* __restrict__ out)
{
  __shared__ _Float16 h_s[2][80][256];
  __shared__ float att_s[256];
  __shared__ float sc_s[40];
  __shared__ float wgt[40];

  const int b   = blockIdx.x;
  const int tid = threadIdx.x;
  const int wv  = tid >> 6;
  const int ln  = tid & 63;
  const int l16 = ln & 15;
  const int lq  = ln >> 4;
  const int hq  = wv & 3;
  const int np2 = wv >> 2;
  const int NT  = np2 ? 2 : 3;

  if (tid < 256) att_s[tid] = att[tid];

  int pA[3] = {0,0,0}, dirA[3] = {0,0,0};
  int bbase[3] = {0,0,0}, bswz[3] = {0,0,0};
  #pragma unroll
  for (int nt=0;nt<3;++nt) if (nt<NT) {
    int s = 48*np2 + 16*nt + l16;
    dirA[nt] = (s >= 40); pA[nt] = s - 40*(s>=40);
    bbase[nt] = s*256; bswz[nt] = (s&7)<<3;
  }
  const int xb = b*480;
  const int ebase = 16*hq + 4*lq;
  const size_t abase = (size_t)(16*hq + l16)*256 + 8*lq;

  float c_reg[4][3][4];
  #pragma unroll
  for (int a1=0;a1<4;++a1)
    #pragma unroll
    for (int a2=0;a2<3;++a2)
      #pragma unroll
      for (int a3=0;a3<4;++a3) c_reg[a1][a2][a3] = 0.0f;

  half4v eR[4][3];
  half8  aR[2][8];
  f32x4  acc[4][3];
  int idxc[3] = {0,0,0};

  NEXT_IDX(0);
  ISSUE_E(0);

  for (int t = 0; t < 12; ++t) {
    const _Float16* hc = &h_s[t&1][0][0];
    _Float16*       hn = &h_s[(t+1)&1][0][0];
    const bool first = (t == 0), last = (t == 11);
    #pragma unroll
    for (int jt = 0; jt < 4; ++jt) {
      ACC_FROM_E();
      if (jt < 3) { ISSUE_E(jt+1); }
      else if (!last) { NEXT_IDX(t+1); ISSUE_E(0); }
      if (!first) {
        #pragma unroll
        for (int kq = 0; kq < 4; ++kq) {
          if (kq < 3)      { ISSUE_A((kq&1)^1, jt, kq+1); }
          else if (jt < 3) { ISSUE_A((kq&1)^1, jt+1, 0); }
          else if (!last)  { ISSUE_A((kq&1)^1, 0, 0); }
          MFMAQ(kq&1, kq);
        }
      } else if (jt == 3) {
        ISSUE_A(0, 0, 0);   // prime A pipeline for t=1
      }
      GATES(jt);
    }
    __syncthreads();
  }

  // ---------- dense: denseT[256 d][48 p] = tanh(WdT x stateT + bd), barrier-free ----------
  const _Float16* hs0 = &h_s[0][0][0];   // final state lives in buf 0
  f32x4 dacc[2][3];
  #pragma unroll
  for (int ml=0;ml<2;++ml)
    #pragma unroll
    for (int nt=0;nt<3;++nt){ f32x4 z0; z0[0]=0.f;z0[1]=0.f;z0[2]=0.f;z0[3]=0.f; dacc[ml][nt]=z0; }
  int pD2[3];
  #pragma unroll
  for (int nt=0;nt<3;++nt){ int p = 16*nt + l16; pD2[nt] = (p < 40) ? p : 39; }

  #pragma unroll
  for (int kq = 0; kq < 8; ++kq) {
    const _Float16* wp0 = wdt + (size_t)(16*(2*wv+0)+l16)*512 + 64*kq + 8*lq;
    const _Float16* wp1 = wdt + (size_t)(16*(2*wv+1)+l16)*512 + 64*kq + 8*lq;
    half8 ad0a = *(const half8*)(wp0), ad0b = *(const half8*)(wp0 + 32);
    half8 ad1a = *(const half8*)(wp1), ad1b = *(const half8*)(wp1 + 32);
    #pragma unroll
    for (int kk2=0;kk2<2;++kk2) {
      half8 bD[3];
      #pragma unroll
      for (int nt=0;nt<3;++nt) {
        int rowD = pD2[nt] + 40*(kq>>2);
        bD[nt] = *(const half8*)(hs0 + rowD*256 + ((64*(kq&3)+32*kk2+8*lq) ^ ((rowD&7)<<3)));
      }
      half8 a0 = kk2 ? ad0b : ad0a;
      half8 a1 = kk2 ? ad1b : ad1a;
      #pragma unroll
      for (int nt=0;nt<3;++nt) {
        dacc[0][nt] = MFMA16(a0, bD[nt], dacc[0][nt]);
        dacc[1][nt] = MFMA16(a1, bD[nt], dacc[1][nt]);
      }
    }
  }
  _Float16* d_s = (_Float16*)&h_s[1][0][0];   // overlay dead buffer: [256 d][56]
  #pragma unroll
  for (int ml = 0; ml < 2; ++ml) {
    int d0 = 16*(2*wv+ml) + 4*lq;
    float4 bv = *(const float4*)&bd[d0];
    float bvr[4] = {bv.x, bv.y, bv.z, bv.w};
    #pragma unroll
    for (int nt = 0; nt < 3; ++nt) {
      int p = 16*nt + l16;
      #pragma unroll
      for (int r = 0; r < 4; ++r) {
        float val = tanh_(dacc[ml][nt][r] + bvr[r]);
        d_s[(d0 + r)*56 + p] = (_Float16)val;
      }
    }
  }
  __syncthreads();
  // ---------- attention: scores by all 8 waves (5 paths each), softmax, weighted sum ----------
  {
    #pragma unroll
    for (int q = 0; q < 5; ++q) {
      int pp = 5*wv + q;
      float s = 0.0f;
      #pragma unroll
      for (int j = 0; j < 4; ++j) {
        int d = 64*j + ln;
        s += (float)d_s[d*56 + pp] * att_s[d];
      }
      #pragma unroll
      for (int off = 32; off > 0; off >>= 1) s += __shfl_xor(s, off);
      if (ln == 0) sc_s[pp] = s;
    }
  }
  __syncthreads();
  if (wv == 0) {
    float sc = (ln < 40) ? sc_s[ln] : -1e30f;
    float m = sc;
    #pragma unroll
    for (int off = 32; off > 0; off >>= 1) m = fmaxf(m, __shfl_xor(m, off));
    float e = __expf(sc - m);
    float se = e;
    #pragma unroll
    for (int off = 32; off > 0; off >>= 1) se += __shfl_xor(se, off);
    if (ln < 40) wgt[ln] = e / se;
  }
  __syncthreads();
  if (tid < 256) {
    float o = 0.0f;
    #pragma unroll 8
    for (int p = 0; p < 40; ++p) o += wgt[p] * (float)d_s[tid*56 + p];
    out[b*256 + tid] = o;
  }
}

extern "C" void kernel_launch(void* const* d_in, const int* in_sizes, int n_in,
                              void* d_out, int out_size, void* d_ws, size_t ws_size,
                              hipStream_t stream)
{
  (void)in_sizes; (void)n_in; (void)out_size;
  const int*   x   = (const int*)  d_in[0];
  const float* emb = (const float*)d_in[1];
  const float* Wk  = (const float*)d_in[2];
  const float* Wr  = (const float*)d_in[3];
  const float* bi  = (const float*)d_in[4];
  const float* Wd  = (const float*)d_in[5];
  const float* bd  = (const float*)d_in[6];
  const float* att = (const float*)d_in[7];
  float* out = (float*)d_out;

  if (ws_size < 42401792u) return;   // need 42.4 MB scratch
  char* ws = (char*)d_ws;
  _Float16* embw = (_Float16*)(ws + 0);          // [20000][1024] fp16 = 40,960,000 B
  _Float16* wrtb = (_Float16*)(ws + 40960000);   // [4][256][256] fp16 =    524,288 B
  _Float16* wkt  = (_Float16*)(ws + 41484288);   // [1024][320]   fp16 =    655,360 B
  _Float16* wdt  = (_Float16*)(ws + 42139648);   // [256][512]    fp16 =    262,144 B

  k0_prep<<<dim3(1280), dim3(256), 0, stream>>>(Wk, Wr, Wd, wkt, wrtb, wdt);
  k1_embw<<<dim3(313), dim3(512), 0, stream>>>(emb, bi, wkt, embw);
  k2_main<<<dim3(256), dim3(512), 0, stream>>>(x, bd, att, embw, wrtb, wdt, out);
}

// Round 5
// 603.520 us; speedup vs baseline: 1.5860x; 1.5855x over previous
//
#include <hip/hip_runtime.h>

using half8  = __attribute__((ext_vector_type(8))) _Float16;
using half4v = __attribute__((ext_vector_type(4))) _Float16;
using f32x4  = __attribute__((ext_vector_type(4))) float;

typedef unsigned int u32;
typedef __attribute__((address_space(1))) const u32 gu32;
typedef __attribute__((address_space(3))) u32 lu32;

#define MFMA16(a,b,c) __builtin_amdgcn_mfma_f32_16x16x32_f16((a),(b),(c),0,0,0)

__device__ __forceinline__ float fexp_(float x){ return exp2f(x * 1.4426950408889634f); }
__device__ __forceinline__ float sig_(float x){ return __builtin_amdgcn_rcpf(1.0f + fexp_(-x)); }
__device__ __forceinline__ float tanh_(float x){
  float t = fexp_(-2.0f * fabsf(x));
  float r = (1.0f - t) * __builtin_amdgcn_rcpf(1.0f + t);
  return copysignf(r, x);
}

// ---------------- K0: weight transposes / fp16 packing ----------------
// wrtb: 16 tiles (jt,kq) of 32KB. Tile element (r, c): r = 64*gate + i (i = row within
// gate block), c = k within the 64-wide K-quarter. Byte offset inside tile:
//   r*128 + ((2*c) ^ ((r&7)<<4))   <- XOR swizzle baked into the GLOBAL layout so that
// global_load_lds (linear dest) + swizzled ds_read form a correct pair (guide G21).
__global__ void k0_prep(const float* __restrict__ Wk, const float* __restrict__ Wr,
                        const float* __restrict__ Wd, _Float16* __restrict__ wkt,
                        _Float16* __restrict__ wrtb, _Float16* __restrict__ wdt)
{
  int i = blockIdx.x * 256 + threadIdx.x;
  if (i < 1024*320) {
    int g = i / 320, k = i - g*320;
    wkt[i] = (_Float16)((k < 300) ? Wk[k*1024 + g] : 0.0f);
  }
  if (i < 4*256*256) {
    int jt = i >> 16, r = (i >> 8) & 255, k = i & 255;
    int g = ((r >> 6) << 8) + (jt << 6) + (r & 63);
    int kq = k >> 6, c = k & 63;
    size_t byteoff = (size_t)(jt*4 + kq)*32768 + (size_t)r*128 + ((2*c) ^ ((r & 7) << 4));
    *(_Float16*)((char*)wrtb + byteoff) = (_Float16)Wr[k*1024 + g];
  }
  if (i < 256*512) {
    int d = i >> 9, k = i & 511;
    wdt[i] = (_Float16)Wd[k*256 + d];
  }
}

// ---------------- K1: embW = emb @ Wk + b  -> embw[v][1024], col = 256*jt + 64*gate + i
__global__ __launch_bounds__(512, 2) void k1_embw(
    const float* __restrict__ emb, const float* __restrict__ bias,
    const _Float16* __restrict__ wkt, _Float16* __restrict__ embw)
{
  __shared__ _Float16 a_s[1024][40];
  __shared__ _Float16 e_s[64][40];
  const int tid = threadIdx.x;
  const int wv = tid >> 6, ln = tid & 63, l16 = ln & 15, lq = ln >> 4;
  const int v0 = blockIdx.x * 64;

  f32x4 acc[8][4];
  #pragma unroll
  for (int ml=0;ml<8;++ml)
    #pragma unroll
    for (int nt=0;nt<4;++nt){ f32x4 z0; z0[0]=0.f;z0[1]=0.f;z0[2]=0.f;z0[3]=0.f; acc[ml][nt]=z0; }

  const int evv = tid >> 2;
  const int ekq = tid & 3;

  for (int c = 0; c < 10; ++c) {
    {
      const uint4* sp  = (const uint4*)(wkt + (size_t)(2*tid)*320 + 32*c);
      uint4 r0=sp[0], r1=sp[1], r2=sp[2], r3=sp[3];
      const uint4* sp2 = (const uint4*)(wkt + (size_t)(2*tid+1)*320 + 32*c);
      uint4 r4=sp2[0], r5=sp2[1], r6=sp2[2], r7=sp2[3];
      uint4* dq  = (uint4*)&a_s[2*tid][0];
      dq[0]=r0; dq[1]=r1; dq[2]=r2; dq[3]=r3;
      uint4* dq2 = (uint4*)&a_s[2*tid+1][0];
      dq2[0]=r4; dq2[1]=r5; dq2[2]=r6; dq2[3]=r7;
    }
    if (tid < 256) {
      int vsrc = v0 + evv; if (vsrc > 19999) vsrc = 19999;
      float f0,f1,f2,f3,f4,f5,f6,f7;
      if (c < 9) {
        const float4* sp = (const float4*)(emb + (size_t)vsrc*300 + 32*c + 8*ekq);
        float4 fa = sp[0], fb = sp[1];
        f0=fa.x; f1=fa.y; f2=fa.z; f3=fa.w; f4=fb.x; f5=fb.y; f6=fb.z; f7=fb.w;
      } else {
        const float* sp = emb + (size_t)vsrc*300;
        int k0 = 288 + 8*ekq;
        f0 = (k0+0<300)? sp[k0+0] : 0.f;  f1 = (k0+1<300)? sp[k0+1] : 0.f;
        f2 = (k0+2<300)? sp[k0+2] : 0.f;  f3 = (k0+3<300)? sp[k0+3] : 0.f;
        f4 = (k0+4<300)? sp[k0+4] : 0.f;  f5 = (k0+5<300)? sp[k0+5] : 0.f;
        f6 = (k0+6<300)? sp[k0+6] : 0.f;  f7 = (k0+7<300)? sp[k0+7] : 0.f;
      }
      half8 hv;
      hv[0]=(_Float16)f0; hv[1]=(_Float16)f1; hv[2]=(_Float16)f2; hv[3]=(_Float16)f3;
      hv[4]=(_Float16)f4; hv[5]=(_Float16)f5; hv[6]=(_Float16)f6; hv[7]=(_Float16)f7;
      *(half8*)&e_s[evv][8*ekq] = hv;
    }
    __syncthreads();
    half8 bf[4];
    #pragma unroll
    for (int nt=0;nt<4;++nt) bf[nt] = *(const half8*)&e_s[16*nt + l16][8*lq];
    #pragma unroll
    for (int ml=0;ml<8;++ml) {
      half8 af = *(const half8*)&a_s[16*(8*wv+ml) + l16][8*lq];
      #pragma unroll
      for (int nt=0;nt<4;++nt) acc[ml][nt] = MFMA16(af, bf[nt], acc[ml][nt]);
    }
    __syncthreads();
  }
  #pragma unroll
  for (int ml=0;ml<8;++ml) {
    int g0 = 16*(8*wv+ml) + 4*lq;
    float4 bv = *(const float4*)&bias[g0];
    float bvr[4] = {bv.x,bv.y,bv.z,bv.w};
    int jt = (g0 >> 6) & 3;
    int c0 = ((g0 >> 8) << 6) + (g0 & 63);
    #pragma unroll
    for (int nt=0;nt<4;++nt) {
      int v = v0 + 16*nt + l16;
      if (v < 20000) {
        half4v hv;
        hv[0]=(_Float16)(acc[ml][nt][0]+bvr[0]);
        hv[1]=(_Float16)(acc[ml][nt][1]+bvr[1]);
        hv[2]=(_Float16)(acc[ml][nt][2]+bvr[2]);
        hv[3]=(_Float16)(acc[ml][nt][3]+bvr[3]);
        *(half4v*)&embw[(size_t)v*1024 + 256*jt + c0] = hv;
      }
    }
  }
}

// ---------------- K2: fused bi-LSTM + dense + attention, 1 block = 1 card ----------------
// 80 seq rows: 0..39 fw paths, 40..79 bw paths. zT = WrT(A) x hT(B).
// A (Wr) is staged global->LDS via global_load_lds into double-buffered 32KB slabs
// (zero VGPR cost; kills the R2-R4 spill + vmcnt serialization). One __syncthreads per
// slice; stage of slice s+1 is issued right after the sync, consumed after the NEXT
// sync -> one full MFMA phase of latency hiding.

#define NEXT_IDX(T) do { \
    _Pragma("unroll") for (int nt=0;nt<3;++nt) if (nt<NT) \
      idxc[nt] = x[xb + pA[nt]*12 + (dirA[nt] ? 11-(T) : (T))]; \
  } while(0)

#define ISSUE_E(JT) do { \
    _Pragma("unroll") for (int nt=0;nt<3;++nt) if (nt<NT) { \
      const _Float16* ep = embw + (size_t)idxc[nt]*1024 + 256*(JT) + ebase; \
      _Pragma("unroll") for (int g=0;g<4;++g) eR[g][nt] = *(const half4v*)(ep + 64*g); \
    } } while(0)

#define ACC_FROM_E() do { \
    _Pragma("unroll") for (int g=0;g<4;++g) \
      _Pragma("unroll") for (int nt=0;nt<3;++nt) if (nt<NT) { \
        f32x4 a0; a0[0]=(float)eR[g][nt][0]; a0[1]=(float)eR[g][nt][1]; \
        a0[2]=(float)eR[g][nt][2]; a0[3]=(float)eR[g][nt][3]; acc[g][nt]=a0; \
      } } while(0)

// stage one 32KB tile (jt,kq) into slab SLAB: 4 x global_load_lds_dwordx4 per thread
#define STAGE(SLAB, TILE) do { \
    const char* sb_ = (const char*)wrtb + (size_t)(TILE)*32768 + tid*16; \
    char* db_ = (char*)&wslab[SLAB][0] + tid*16; \
    _Pragma("unroll") for (int q=0;q<4;++q) \
      __builtin_amdgcn_global_load_lds((gu32*)(sb_ + q*8192), (lu32*)(db_ + q*8192), 16, 0, 0); \
  } while(0)

// A from LDS slab (swizzled layout matches k0's baked swizzle), B from h LDS
#define MFMAQL(SLAB, KQ) do { \
    const char* wc_ = (const char*)&wslab[SLAB][0]; \
    _Pragma("unroll") for (int kk2=0;kk2<2;++kk2) { \
      half8 bFv[3]; \
      _Pragma("unroll") for (int nt=0;nt<3;++nt) if (nt<NT) \
        bFv[nt] = *(const half8*)(hc + bbase[nt] + ((64*(KQ)+32*kk2+8*lq) ^ bswz[nt])); \
      _Pragma("unroll") for (int g=0;g<4;++g) { \
        half8 aFv = *(const half8*)(wc_ + abase0 + g*8192 + ((kk2*64 + lq*16) ^ aswz)); \
        _Pragma("unroll") for (int nt=0;nt<3;++nt) if (nt<NT) \
          acc[g][nt] = MFMA16(aFv, bFv[nt], acc[g][nt]); \
      } \
    } } while(0)

#define GATES(JT) do { \
    _Pragma("unroll") for (int nt=0;nt<3;++nt) if (nt<NT) { \
      half4v hv; \
      _Pragma("unroll") for (int r=0;r<4;++r) { \
        float zi=acc[0][nt][r], zf=acc[1][nt][r], zg=acc[2][nt][r], zo=acc[3][nt][r]; \
        float cn = sig_(zf)*c_reg[JT][nt][r] + sig_(zi)*tanh_(zg); \
        c_reg[JT][nt][r]=cn; hv[r]=(_Float16)(sig_(zo)*tanh_(cn)); \
      } \
      *(half4v*)(hn + bbase[nt] + ((64*(JT)+16*hq+4*lq) ^ bswz[nt])) = hv; \
    } } while(0)

__global__ __launch_bounds__(512, 2) void k2_main(
    const int* __restrict__ x, const float* __restrict__ bd,
    const float* __restrict__ att, const _Float16* __restrict__ embw,
    const _Float16* __restrict__ wrtb, const _Float16* __restrict__ wdt,
    float* __restrict__ out)
{
  __shared__ _Float16 h_s[2][80][256];      // 80 KB
  __shared__ _Float16 wslab[2][16384];      // 64 KB: Wr tile double-buffer
  __shared__ float att_s[256];
  __shared__ float sc_s[40];
  __shared__ float wgt[40];

  const int b   = blockIdx.x;
  const int tid = threadIdx.x;
  const int wv  = tid >> 6;
  const int ln  = tid & 63;
  const int l16 = ln & 15;
  const int lq  = ln >> 4;
  const int hq  = wv & 3;
  const int np2 = wv >> 2;
  const int NT  = np2 ? 2 : 3;

  if (tid < 256) att_s[tid] = att[tid];

  int pA[3] = {0,0,0}, dirA[3] = {0,0,0};
  int bbase[3] = {0,0,0}, bswz[3] = {0,0,0};
  #pragma unroll
  for (int nt=0;nt<3;++nt) if (nt<NT) {
    int s = 48*np2 + 16*nt + l16;
    dirA[nt] = (s >= 40); pA[nt] = s - 40*(s>=40);
    bbase[nt] = s*256; bswz[nt] = (s&7)<<3;
  }
  const int xb = b*480;
  const int ebase = 16*hq + 4*lq;
  const int abase0 = (16*hq + l16)*128;   // byte row base in Wr tile
  const int aswz   = (l16 & 7) << 4;      // byte XOR swizzle (matches k0 layout)

  float c_reg[4][3][4];
  #pragma unroll
  for (int a1=0;a1<4;++a1)
    #pragma unroll
    for (int a2=0;a2<3;++a2)
      #pragma unroll
      for (int a3=0;a3<4;++a3) c_reg[a1][a2][a3] = 0.0f;

  half4v eR[4][3];
  f32x4  acc[4][3];
  int idxc[3] = {0,0,0};

  NEXT_IDX(0);
  ISSUE_E(0);

  // ---- t = 0: z = xg (h=0, no MFMA) ----
  {
    _Float16* hn = &h_s[1][0][0];
    #pragma unroll
    for (int jt = 0; jt < 4; ++jt) {
      ACC_FROM_E();
      if (jt < 3) { ISSUE_E(jt+1); }
      else        { NEXT_IDX(1); ISSUE_E(0); }
      GATES(jt);
    }
  }
  STAGE(0, 0);   // prime slab 0 with tile 0; drained by first in-loop sync

  // ---- t = 1..11: 16 slices/step, one sync per slice ----
  for (int t = 1; t < 12; ++t) {
    const _Float16* hc = &h_s[t&1][0][0];
    _Float16*       hn = &h_s[(t+1)&1][0][0];
    const bool last = (t == 11);
    #pragma unroll
    for (int s = 0; s < 16; ++s) {
      const int jt = s >> 2, kq = s & 3;
      __syncthreads();                       // slab[s&1] staged; prev slab free
      if (!(last && s == 15)) { STAGE((s+1)&1, (s+1)&15); }
      if (kq == 0) {
        ACC_FROM_E();
        if (jt < 3)    { ISSUE_E(jt+1); }
        else if (!last){ NEXT_IDX(t+1); ISSUE_E(0); }
      }
      MFMAQL(s&1, kq);
      if (kq == 3) GATES(jt);
    }
  }
  __syncthreads();   // h buf0 (final state) committed

  // ---------- dense: denseT[256 d][48 p] = tanh(WdT x stateT + bd) ----------
  const _Float16* hs0 = &h_s[0][0][0];
  f32x4 dacc[2][3];
  #pragma unroll
  for (int ml=0;ml<2;++ml)
    #pragma unroll
    for (int nt=0;nt<3;++nt){ f32x4 z0; z0[0]=0.f;z0[1]=0.f;z0[2]=0.f;z0[3]=0.f; dacc[ml][nt]=z0; }
  int pD2[3];
  #pragma unroll
  for (int nt=0;nt<3;++nt){ int p = 16*nt + l16; pD2[nt] = (p < 40) ? p : 39; }

  #pragma unroll
  for (int kq = 0; kq < 8; ++kq) {
    const _Float16* wp0 = wdt + (size_t)(16*(2*wv+0)+l16)*512 + 64*kq + 8*lq;
    const _Float16* wp1 = wdt + (size_t)(16*(2*wv+1)+l16)*512 + 64*kq + 8*lq;
    half8 ad0a = *(const half8*)(wp0), ad0b = *(const half8*)(wp0 + 32);
    half8 ad1a = *(const half8*)(wp1), ad1b = *(const half8*)(wp1 + 32);
    #pragma unroll
    for (int kk2=0;kk2<2;++kk2) {
      half8 bD[3];
      #pragma unroll
      for (int nt=0;nt<3;++nt) {
        int rowD = pD2[nt] + 40*(kq>>2);
        bD[nt] = *(const half8*)(hs0 + rowD*256 + ((64*(kq&3)+32*kk2+8*lq) ^ ((rowD&7)<<3)));
      }
      half8 a0 = kk2 ? ad0b : ad0a;
      half8 a1 = kk2 ? ad1b : ad1a;
      #pragma unroll
      for (int nt=0;nt<3;++nt) {
        dacc[0][nt] = MFMA16(a0, bD[nt], dacc[0][nt]);
        dacc[1][nt] = MFMA16(a1, bD[nt], dacc[1][nt]);
      }
    }
  }
  _Float16* d_s = (_Float16*)&h_s[1][0][0];   // overlay dead buffer: [256 d][56]
  #pragma unroll
  for (int ml = 0; ml < 2; ++ml) {
    int d0 = 16*(2*wv+ml) + 4*lq;
    float4 bv = *(const float4*)&bd[d0];
    float bvr[4] = {bv.x, bv.y, bv.z, bv.w};
    #pragma unroll
    for (int nt = 0; nt < 3; ++nt) {
      int p = 16*nt + l16;
      #pragma unroll
      for (int r = 0; r < 4; ++r) {
        float val = tanh_(dacc[ml][nt][r] + bvr[r]);
        d_s[(d0 + r)*56 + p] = (_Float16)val;
      }
    }
  }
  __syncthreads();
  // ---------- attention: scores by all 8 waves (5 paths each), softmax, weighted sum ----------
  {
    #pragma unroll
    for (int q = 0; q < 5; ++q) {
      int pp = 5*wv + q;
      float s = 0.0f;
      #pragma unroll
      for (int j = 0; j < 4; ++j) {
        int d = 64*j + ln;
        s += (float)d_s[d*56 + pp] * att_s[d];
      }
      #pragma unroll
      for (int off = 32; off > 0; off >>= 1) s += __shfl_xor(s, off);
      if (ln == 0) sc_s[pp] = s;
    }
  }
  __syncthreads();
  if (wv == 0) {
    float sc = (ln < 40) ? sc_s[ln] : -1e30f;
    float m = sc;
    #pragma unroll
    for (int off = 32; off > 0; off >>= 1) m = fmaxf(m, __shfl_xor(m, off));
    float e = __expf(sc - m);
    float se = e;
    #pragma unroll
    for (int off = 32; off > 0; off >>= 1) se += __shfl_xor(se, off);
    if (ln < 40) wgt[ln] = e / se;
  }
  __syncthreads();
  if (tid < 256) {
    float o = 0.0f;
    #pragma unroll 8
    for (int p = 0; p < 40; ++p) o += wgt[p] * (float)d_s[tid*56 + p];
    out[b*256 + tid] = o;
  }
}

extern "C" void kernel_launch(void* const* d_in, const int* in_sizes, int n_in,
                              void* d_out, int out_size, void* d_ws, size_t ws_size,
                              hipStream_t stream)
{
  (void)in_sizes; (void)n_in; (void)out_size;
  const int*   x   = (const int*)  d_in[0];
  const float* emb = (const float*)d_in[1];
  const float* Wk  = (const float*)d_in[2];
  const float* Wr  = (const float*)d_in[3];
  const float* bi  = (const float*)d_in[4];
  const float* Wd  = (const float*)d_in[5];
  const float* bd  = (const float*)d_in[6];
  const float* att = (const float*)d_in[7];
  float* out = (float*)d_out;

  if (ws_size < 42401792u) return;   // need 42.4 MB scratch
  char* ws = (char*)d_ws;
  _Float16* embw = (_Float16*)(ws + 0);          // [20000][1024] fp16 = 40,960,000 B
  _Float16* wrtb = (_Float16*)(ws + 40960000);   // 16 x 32KB swizzled tiles = 524,288 B
  _Float16* wkt  = (_Float16*)(ws + 41484288);   // [1024][320]   fp16 =    655,360 B
  _Float16* wdt  = (_Float16*)(ws + 42139648);   // [256][512]    fp16 =    262,144 B

  k0_prep<<<dim3(1280), dim3(256), 0, stream>>>(Wk, Wr, Wd, wkt, wrtb, wdt);
  k1_embw<<<dim3(313), dim3(512), 0, stream>>>(emb, bi, wkt, embw);
  k2_main<<<dim3(256), dim3(512), 0, stream>>>(x, bd, att, embw, wrtb, wdt, out);
}

// Round 6
// 588.532 us; speedup vs baseline: 1.6264x; 1.0255x over previous
//
#include <hip/hip_runtime.h>

using half8  = __attribute__((ext_vector_type(8))) _Float16;
using half4v = __attribute__((ext_vector_type(4))) _Float16;
using f32x4  = __attribute__((ext_vector_type(4))) float;

#define MFMA16(a,b,c) __builtin_amdgcn_mfma_f32_16x16x32_f16((a),(b),(c),0,0,0)
#define LOG2E 1.4426950408889634f
#define KTC  -2.8853900817779268f   /* -2*log2(e): tanh(c) = 2/(1+2^(c*KTC)) - 1 */

__device__ __forceinline__ float sigp_(float zp){           // sigmoid, zp pre-scaled by log2e
  return __builtin_amdgcn_rcpf(1.0f + exp2f(-zp));
}
__device__ __forceinline__ float tanhp_(float zp){          // tanh, zp pre-scaled by log2e
  return fmaf(2.0f, __builtin_amdgcn_rcpf(1.0f + exp2f(-2.0f*zp)), -1.0f);
}
__device__ __forceinline__ float tanhn_(float x){           // tanh, natural units
  return fmaf(2.0f, __builtin_amdgcn_rcpf(1.0f + exp2f(x*KTC)), -1.0f);
}

// ---------------- K0: weight transposes / fp16 packing ----------------
// wkt, wrtb carry a baked log2(e) factor so gates use raw exp2.
// wrtb linear: [4 jt][256 r][256 k], r = 64*gate + i  <-> g = 256*gate + 64*jt + i
__global__ void k0_prep(const float* __restrict__ Wk, const float* __restrict__ Wr,
                        const float* __restrict__ Wd, _Float16* __restrict__ wkt,
                        _Float16* __restrict__ wrtb, _Float16* __restrict__ wdt)
{
  int i = blockIdx.x * 256 + threadIdx.x;
  if (i < 1024*320) {
    int g = i / 320, k = i - g*320;
    wkt[i] = (_Float16)((k < 300) ? Wk[k*1024 + g]*LOG2E : 0.0f);
  }
  if (i < 4*256*256) {
    int jt = i >> 16, r = (i >> 8) & 255, k = i & 255;
    int g = ((r >> 6) << 8) + (jt << 6) + (r & 63);
    wrtb[i] = (_Float16)(Wr[k*1024 + g]*LOG2E);
  }
  if (i < 256*512) {
    int d = i >> 9, k = i & 511;
    wdt[i] = (_Float16)Wd[k*256 + d];
  }
}

// ---------------- K1: embW = (emb @ Wk + b)*log2e -> embw[v][1024] ----------------
__global__ __launch_bounds__(512, 2) void k1_embw(
    const float* __restrict__ emb, const float* __restrict__ bias,
    const _Float16* __restrict__ wkt, _Float16* __restrict__ embw)
{
  __shared__ _Float16 a_s[1024][40];
  __shared__ _Float16 e_s[64][40];
  const int tid = threadIdx.x;
  const int wv = tid >> 6, ln = tid & 63, l16 = ln & 15, lq = ln >> 4;
  const int v0 = blockIdx.x * 64;

  f32x4 acc[8][4];
  #pragma unroll
  for (int ml=0;ml<8;++ml)
    #pragma unroll
    for (int nt=0;nt<4;++nt){ f32x4 z0; z0[0]=0.f;z0[1]=0.f;z0[2]=0.f;z0[3]=0.f; acc[ml][nt]=z0; }

  const int evv = tid >> 2;
  const int ekq = tid & 3;

  for (int c = 0; c < 10; ++c) {
    {
      const uint4* sp  = (const uint4*)(wkt + (size_t)(2*tid)*320 + 32*c);
      uint4 r0=sp[0], r1=sp[1], r2=sp[2], r3=sp[3];
      const uint4* sp2 = (const uint4*)(wkt + (size_t)(2*tid+1)*320 + 32*c);
      uint4 r4=sp2[0], r5=sp2[1], r6=sp2[2], r7=sp2[3];
      uint4* dq  = (uint4*)&a_s[2*tid][0];
      dq[0]=r0; dq[1]=r1; dq[2]=r2; dq[3]=r3;
      uint4* dq2 = (uint4*)&a_s[2*tid+1][0];
      dq2[0]=r4; dq2[1]=r5; dq2[2]=r6; dq2[3]=r7;
    }
    if (tid < 256) {
      int vsrc = v0 + evv; if (vsrc > 19999) vsrc = 19999;
      float f0,f1,f2,f3,f4,f5,f6,f7;
      if (c < 9) {
        const float4* sp = (const float4*)(emb + (size_t)vsrc*300 + 32*c + 8*ekq);
        float4 fa = sp[0], fb = sp[1];
        f0=fa.x; f1=fa.y; f2=fa.z; f3=fa.w; f4=fb.x; f5=fb.y; f6=fb.z; f7=fb.w;
      } else {
        const float* sp = emb + (size_t)vsrc*300;
        int k0 = 288 + 8*ekq;
        f0 = (k0+0<300)? sp[k0+0] : 0.f;  f1 = (k0+1<300)? sp[k0+1] : 0.f;
        f2 = (k0+2<300)? sp[k0+2] : 0.f;  f3 = (k0+3<300)? sp[k0+3] : 0.f;
        f4 = (k0+4<300)? sp[k0+4] : 0.f;  f5 = (k0+5<300)? sp[k0+5] : 0.f;
        f6 = (k0+6<300)? sp[k0+6] : 0.f;  f7 = (k0+7<300)? sp[k0+7] : 0.f;
      }
      half8 hv;
      hv[0]=(_Float16)f0; hv[1]=(_Float16)f1; hv[2]=(_Float16)f2; hv[3]=(_Float16)f3;
      hv[4]=(_Float16)f4; hv[5]=(_Float16)f5; hv[6]=(_Float16)f6; hv[7]=(_Float16)f7;
      *(half8*)&e_s[evv][8*ekq] = hv;
    }
    __syncthreads();
    half8 bf[4];
    #pragma unroll
    for (int nt=0;nt<4;++nt) bf[nt] = *(const half8*)&e_s[16*nt + l16][8*lq];
    #pragma unroll
    for (int ml=0;ml<8;++ml) {
      half8 af = *(const half8*)&a_s[16*(8*wv+ml) + l16][8*lq];
      #pragma unroll
      for (int nt=0;nt<4;++nt) acc[ml][nt] = MFMA16(af, bf[nt], acc[ml][nt]);
    }
    __syncthreads();
  }
  #pragma unroll
  for (int ml=0;ml<8;++ml) {
    int g0 = 16*(8*wv+ml) + 4*lq;
    float4 bv = *(const float4*)&bias[g0];
    float bvr[4] = {bv.x*LOG2E, bv.y*LOG2E, bv.z*LOG2E, bv.w*LOG2E};
    int jt = (g0 >> 6) & 3;
    int c0 = ((g0 >> 8) << 6) + (g0 & 63);
    #pragma unroll
    for (int nt=0;nt<4;++nt) {
      int v = v0 + 16*nt + l16;
      if (v < 20000) {
        half4v hv;
        hv[0]=(_Float16)(acc[ml][nt][0]+bvr[0]);
        hv[1]=(_Float16)(acc[ml][nt][1]+bvr[1]);
        hv[2]=(_Float16)(acc[ml][nt][2]+bvr[2]);
        hv[3]=(_Float16)(acc[ml][nt][3]+bvr[3]);
        *(half4v*)&embw[(size_t)v*1024 + 256*jt + c0] = hv;
      }
    }
  }
}

// ---------------- K2: fused bi-LSTM + dense + attention ----------------
// 1 block = 1 card. 256 threads = 4 waves = 1 wave/SIMD -> 512-reg/wave budget,
// no spill (R2-R5's 69-148MB scratch traffic), and plain global->VGPR A-prefetch
// is NOT drained by barriers. One __syncthreads per time step (h dbuf swap).
// Wave wv = hq owns 16 gatecols per (gate, jt-chunk); covers all 5 seq row-tiles.

#define NEXT_IDXC(T) do { \
    _Pragma("unroll") for (int nt=0;nt<5;++nt) \
      idxc[nt] = x[xb + pA[nt]*12 + (dirA[nt] ? 11-(T) : (T))]; \
  } while(0)

#define NEXT_IDXN(T) do { \
    _Pragma("unroll") for (int nt=0;nt<5;++nt) \
      idxn[nt] = x[xb + pA[nt]*12 + (dirA[nt] ? 11-(T) : (T))]; \
  } while(0)

#define ISSUE_E_I(IDX, JT) do { \
    _Pragma("unroll") for (int nt=0;nt<5;++nt) { \
      const _Float16* ep = embw + (size_t)IDX[nt]*1024 + 256*(JT) + ebase; \
      _Pragma("unroll") for (int g=0;g<4;++g) eR[g][nt] = *(const half4v*)(ep + 64*g); \
    } } while(0)

#define ISSUE_E(JT) ISSUE_E_I(idxc, JT)

#define ACC_FROM_E() do { \
    _Pragma("unroll") for (int g=0;g<4;++g) \
      _Pragma("unroll") for (int nt=0;nt<5;++nt) { \
        f32x4 a0; a0[0]=(float)eR[g][nt][0]; a0[1]=(float)eR[g][nt][1]; \
        a0[2]=(float)eR[g][nt][2]; a0[3]=(float)eR[g][nt][3]; acc[g][nt]=a0; \
      } } while(0)

#define ISSUE_A(P,JT,KQ) do { \
    const _Float16* ap = wrtb + abase + 65536*(JT) + 64*(KQ); \
    _Pragma("unroll") for (int g=0;g<4;++g) { \
      aR[P][2*g+0] = *(const half8*)(ap + 16384*g); \
      aR[P][2*g+1] = *(const half8*)(ap + 16384*g + 32); \
    } } while(0)

#define MFMAQ(P,KQ) do { \
    _Pragma("unroll") for (int kk2=0;kk2<2;++kk2) { \
      half8 bF[5]; \
      _Pragma("unroll") for (int nt=0;nt<5;++nt) \
        bF[nt] = *(const half8*)(hc + bbase[nt] + ((64*(KQ)+32*kk2+8*lq) ^ bswz[nt])); \
      _Pragma("unroll") for (int g=0;g<4;++g) \
        _Pragma("unroll") for (int nt=0;nt<5;++nt) \
          acc[g][nt] = MFMA16(aR[P][2*g+kk2], bF[nt], acc[g][nt]); \
    } } while(0)

#define GATES(JT) do { \
    _Pragma("unroll") for (int nt=0;nt<5;++nt) { \
      half4v hv; \
      _Pragma("unroll") for (int r=0;r<4;++r) { \
        float zi=acc[0][nt][r], zf=acc[1][nt][r], zg=acc[2][nt][r], zo=acc[3][nt][r]; \
        float cn = fmaf(sigp_(zf), c_reg[JT][nt][r], sigp_(zi)*tanhp_(zg)); \
        c_reg[JT][nt][r]=cn; hv[r]=(_Float16)(sigp_(zo)*tanhn_(cn)); \
      } \
      *(half4v*)(hn + bbase[nt] + ((64*(JT)+16*hq+4*lq) ^ bswz[nt])) = hv; \
    } } while(0)

__global__ __launch_bounds__(256, 1) void k2_main(
    const int* __restrict__ x, const float* __restrict__ bd,
    const float* __restrict__ att, const _Float16* __restrict__ embw,
    const _Float16* __restrict__ wrtb, const _Float16* __restrict__ wdt,
    float* __restrict__ out)
{
  __shared__ _Float16 h_s[2][80][256];   // 80 KB (dbuf) -> 1 block/CU
  __shared__ float att_s[256];
  __shared__ float sc_s[40];
  __shared__ float wgt[40];

  const int b   = blockIdx.x;
  const int tid = threadIdx.x;
  const int wv  = tid >> 6;       // wave id = hq (16-col subtile in each 64-col chunk)
  const int ln  = tid & 63;
  const int l16 = ln & 15;
  const int lq  = ln >> 4;
  const int hq  = wv;

  att_s[tid] = att[tid];

  int pA[5], dirA[5], bbase[5], bswz[5];
  #pragma unroll
  for (int nt=0;nt<5;++nt) {
    int s = 16*nt + l16;                 // seq row 0..79: 0..39 fw, 40..79 bw
    dirA[nt] = (s >= 40); pA[nt] = s - 40*(s>=40);
    bbase[nt] = s*256; bswz[nt] = (s&7)<<3;
  }
  const int xb = b*480;
  const int ebase = 16*hq + 4*lq;
  const size_t abase = (size_t)(16*hq + l16)*256 + 8*lq;

  float c_reg[4][5][4];
  #pragma unroll
  for (int a1=0;a1<4;++a1)
    #pragma unroll
    for (int a2=0;a2<5;++a2)
      #pragma unroll
      for (int a3=0;a3<4;++a3) c_reg[a1][a2][a3] = 0.0f;

  half4v eR[4][5];
  half8  aR[2][8];
  f32x4  acc[4][5];
  int idxc[5], idxn[5];

  NEXT_IDXC(0);
  ISSUE_E(0);

  // ---- t = 0: z = xg (h=0, no MFMA) ----
  {
    _Float16* hn = &h_s[1][0][0];
    #pragma unroll
    for (int jt = 0; jt < 4; ++jt) {
      ACC_FROM_E();
      if (jt < 3) { ISSUE_E(jt+1); }
      else        { NEXT_IDXC(1); ISSUE_E(0); }
      GATES(jt);
    }
    ISSUE_A(0, 0, 0);                    // prime A dbuf for t=1 slice 0
  }

  // ---- t = 1..11: 16 slices/step, ONE barrier/step ----
  for (int t = 1; t < 12; ++t) {
    __syncthreads();                     // h[t&1] committed by all waves
    const _Float16* hc = &h_s[t&1][0][0];
    _Float16*       hn = &h_s[(t+1)&1][0][0];
    const bool last = (t == 11);
    #pragma unroll
    for (int jt = 0; jt < 4; ++jt) {
      ACC_FROM_E();
      if (jt < 3)      { ISSUE_E(jt+1); }
      if (jt == 2 && !last) { NEXT_IDXN(t+1); }
      if (jt == 3 && !last) {
        ISSUE_E_I(idxn, 0);
        #pragma unroll
        for (int nt=0;nt<5;++nt) idxc[nt] = idxn[nt];
      }
      #pragma unroll
      for (int kq = 0; kq < 4; ++kq) {
        const int u = 4*jt + kq;
        if (u < 15)      { ISSUE_A((u+1)&1, (u+1)>>2, (u+1)&3); }
        else if (!last)  { ISSUE_A(0, 0, 0); }
        MFMAQ(u&1, kq);
      }
      GATES(jt);
    }
  }
  __syncthreads();                       // final state (h_s[0]) committed

  // ---------- dense: denseT[256 d][48 p] = tanh(WdT x stateT + bd) ----------
  const _Float16* hs0 = &h_s[0][0][0];
  f32x4 dacc[4][3];
  #pragma unroll
  for (int ml=0;ml<4;++ml)
    #pragma unroll
    for (int nt=0;nt<3;++nt){ f32x4 z0; z0[0]=0.f;z0[1]=0.f;z0[2]=0.f;z0[3]=0.f; dacc[ml][nt]=z0; }
  int pD2[3];
  #pragma unroll
  for (int nt=0;nt<3;++nt){ int p = 16*nt + l16; pD2[nt] = (p < 40) ? p : 39; }

  #pragma unroll
  for (int kq = 0; kq < 8; ++kq) {
    half8 adA[4], adB[4];
    #pragma unroll
    for (int ml=0;ml<4;++ml) {
      const _Float16* wp = wdt + (size_t)(16*(4*wv+ml)+l16)*512 + 64*kq + 8*lq;
      adA[ml] = *(const half8*)(wp);
      adB[ml] = *(const half8*)(wp + 32);
    }
    #pragma unroll
    for (int kk2=0;kk2<2;++kk2) {
      half8 bD[3];
      #pragma unroll
      for (int nt=0;nt<3;++nt) {
        int rowD = pD2[nt] + 40*(kq>>2);
        bD[nt] = *(const half8*)(hs0 + rowD*256 + ((64*(kq&3)+32*kk2+8*lq) ^ ((rowD&7)<<3)));
      }
      #pragma unroll
      for (int ml=0;ml<4;++ml) {
        half8 a0 = kk2 ? adB[ml] : adA[ml];
        #pragma unroll
        for (int nt=0;nt<3;++nt) dacc[ml][nt] = MFMA16(a0, bD[nt], dacc[ml][nt]);
      }
    }
  }
  _Float16* d_s = (_Float16*)&h_s[1][0][0];   // overlay dead buffer: [256 d][56]
  #pragma unroll
  for (int ml = 0; ml < 4; ++ml) {
    int d0 = 16*(4*wv+ml) + 4*lq;
    float4 bv = *(const float4*)&bd[d0];
    float bvr[4] = {bv.x, bv.y, bv.z, bv.w};
    #pragma unroll
    for (int nt = 0; nt < 3; ++nt) {
      int p = 16*nt + l16;
      #pragma unroll
      for (int r = 0; r < 4; ++r) {
        float val = tanhn_(dacc[ml][nt][r] + bvr[r]);
        d_s[(d0 + r)*56 + p] = (_Float16)val;
      }
    }
  }
  __syncthreads();
  // ---------- attention: 10 path-scores per wave, softmax, weighted sum ----------
  {
    #pragma unroll
    for (int q = 0; q < 10; ++q) {
      int pp = 10*wv + q;
      float s = 0.0f;
      #pragma unroll
      for (int j = 0; j < 4; ++j) {
        int d = 64*j + ln;
        s += (float)d_s[d*56 + pp] * att_s[d];
      }
      #pragma unroll
      for (int off = 32; off > 0; off >>= 1) s += __shfl_xor(s, off);
      if (ln == 0) sc_s[pp] = s;
    }
  }
  __syncthreads();
  if (wv == 0) {
    float sc = (ln < 40) ? sc_s[ln] : -1e30f;
    float m = sc;
    #pragma unroll
    for (int off = 32; off > 0; off >>= 1) m = fmaxf(m, __shfl_xor(m, off));
    float e = __expf(sc - m);
    float se = e;
    #pragma unroll
    for (int off = 32; off > 0; off >>= 1) se += __shfl_xor(se, off);
    if (ln < 40) wgt[ln] = e / se;
  }
  __syncthreads();
  {
    float o = 0.0f;
    #pragma unroll 8
    for (int p = 0; p < 40; ++p) o += wgt[p] * (float)d_s[tid*56 + p];
    out[b*256 + tid] = o;
  }
}

extern "C" void kernel_launch(void* const* d_in, const int* in_sizes, int n_in,
                              void* d_out, int out_size, void* d_ws, size_t ws_size,
                              hipStream_t stream)
{
  (void)in_sizes; (void)n_in; (void)out_size;
  const int*   x   = (const int*)  d_in[0];
  const float* emb = (const float*)d_in[1];
  const float* Wk  = (const float*)d_in[2];
  const float* Wr  = (const float*)d_in[3];
  const float* bi  = (const float*)d_in[4];
  const float* Wd  = (const float*)d_in[5];
  const float* bd  = (const float*)d_in[6];
  const float* att = (const float*)d_in[7];
  float* out = (float*)d_out;

  if (ws_size < 42401792u) return;   // need 42.4 MB scratch
  char* ws = (char*)d_ws;
  _Float16* embw = (_Float16*)(ws + 0);          // [20000][1024] fp16 = 40,960,000 B
  _Float16* wrtb = (_Float16*)(ws + 40960000);   // [4][256][256] fp16 =    524,288 B
  _Float16* wkt  = (_Float16*)(ws + 41484288);   // [1024][320]   fp16 =    655,360 B
  _Float16* wdt  = (_Float16*)(ws + 42139648);   // [256][512]    fp16 =    262,144 B

  k0_prep<<<dim3(1280), dim3(256), 0, stream>>>(Wk, Wr, Wd, wkt, wrtb, wdt);
  k1_embw<<<dim3(313), dim3(512), 0, stream>>>(emb, bi, wkt, embw);
  k2_main<<<dim3(256), dim3(256), 0, stream>>>(x, bd, att, embw, wrtb, wdt, out);
}